// Round 4
// baseline (488.521 us; speedup 1.0000x reference)
//
#include <hip/hip_runtime.h>
#include <hip/hip_bf16.h>
#include <stdint.h>

#define N_NODES 50000
#define N_EDGES 800000
#define HDIM 64

typedef __attribute__((ext_vector_type(8))) short short8;
typedef __attribute__((ext_vector_type(4))) float floatx4;

__device__ __forceinline__ float bf2f(unsigned short u) {
    union { unsigned int i; float f; } v; v.i = ((unsigned int)u) << 16; return v.f;
}
__device__ __forceinline__ unsigned short f2bf(float f) {
    __hip_bfloat16 h = __float2bfloat16(f);
    return *reinterpret_cast<unsigned short*>(&h);
}

// Detect whether a float tensor was stored as bf16 (1) or f32 (0).
__device__ __forceinline__ int detect_is_bf16(const unsigned short* p) {
    int cnt = 0;
    #pragma unroll
    for (int i = 0; i < 64; ++i) {
        unsigned short b = p[i];
        int e = (b >> 7) & 0xFF;
        cnt += ((e >= 97 && e <= 157) || (b & 0x7FFF) == 0) ? 1 : 0;
    }
    return cnt >= 56;
}

__device__ __forceinline__ float getf(const void* p, unsigned int i, int isb) {
    return isb ? bf2f(((const unsigned short*)p)[i]) : ((const float*)p)[i];
}

// 8 contiguous elements -> bf16 fragment
__device__ __forceinline__ short8 get8bf(const void* p, unsigned int i, int isb) {
    if (isb) {
        return *reinterpret_cast<const short8*>((const short*)p + i);
    } else {
        const float4 f0 = *reinterpret_cast<const float4*>((const float*)p + i);
        const float4 f1 = *reinterpret_cast<const float4*>((const float*)p + i + 4);
        short8 a;
        a[0] = (short)f2bf(f0.x); a[1] = (short)f2bf(f0.y);
        a[2] = (short)f2bf(f0.z); a[3] = (short)f2bf(f0.w);
        a[4] = (short)f2bf(f1.x); a[5] = (short)f2bf(f1.y);
        a[6] = (short)f2bf(f1.z); a[7] = (short)f2bf(f1.w);
        return a;
    }
}

// Compiler-only memory fence (free) — blocks LDS write/read reordering.
#define COMPILER_FENCE() asm volatile("" ::: "memory")
// HW wait: lgkmcnt(0) only (vmcnt=63, expcnt=7 untouched) — drains LDS writes
// without draining in-flight global loads/atomics.
#define WAIT_LDS() __builtin_amdgcn_s_waitcnt(0xC07F)

// ---------------------------------------------------------------------------
// Edge kernel: per wave, a 16-edge MFMA M-tile. NO block barriers in the loop:
// the layer1->layer2 LDS re-layout is wave-local (sA2[wave]) and ordered with
// a compiler fence + lgkmcnt(0). Atomics are fire-and-forget until kernel end.
// ---------------------------------------------------------------------------
__global__ __launch_bounds__(256, 4) void edge_kernel(
    const void* __restrict__ feat,    // [N][64] bf16 or f32
    const void* __restrict__ xpos,    // [N][3]
    const int* __restrict__ src,
    const int* __restrict__ dst,
    const void* __restrict__ W1,      // [129][64] row-major
    const void* __restrict__ b1,
    const void* __restrict__ W2,      // [64][64]
    const void* __restrict__ b2,
    const void* __restrict__ we,
    const void* __restrict__ be,
    float* __restrict__ msum,         // [N][64] f32 (zeroed)
    unsigned int msum_cap)
{
    __shared__ __align__(16) short sA2[4][16][72];  // per-wave 16x64 tile, stride 144B

    const int isb  = detect_is_bf16((const unsigned short*)feat);
    const int tid  = threadIdx.x;
    const int wave = tid >> 6;
    const int lane = tid & 63;
    const int l15  = lane & 15;
    const int quad = lane >> 4;

    // ---- persistent B fragments: lane holds B[k=quad*8+j][n=l15+16*nt] ----
    short8 bw1[4][4];
    #pragma unroll
    for (int c = 0; c < 4; ++c)
        #pragma unroll
        for (int nt = 0; nt < 4; ++nt) {
            short8 b;
            #pragma unroll
            for (int j = 0; j < 8; ++j)
                b[j] = (short)f2bf(getf(W1, (c * 32 + quad * 8 + j) * 64 + nt * 16 + l15, isb));
            bw1[c][nt] = b;
        }
    short8 bw2[2][4];
    #pragma unroll
    for (int c = 0; c < 2; ++c)
        #pragma unroll
        for (int nt = 0; nt < 4; ++nt) {
            short8 b;
            #pragma unroll
            for (int j = 0; j < 8; ++j)
                b[j] = (short)f2bf(getf(W2, (c * 32 + quad * 8 + j) * 64 + nt * 16 + l15, isb));
            bw2[c][nt] = b;
        }
    float b1r[4], w1lr[4], b2r[4], wer[4];
    #pragma unroll
    for (int nt = 0; nt < 4; ++nt) {
        int n = nt * 16 + l15;
        b1r[nt]  = getf(b1, n, isb);
        w1lr[nt] = getf(W1, 128 * 64 + n, isb);   // sqd row of W1
        b2r[nt]  = getf(b2, n, isb);
        wer[nt]  = getf(we, n, isb);
    }
    const float ber = getf(be, 0, isb);
    const int rowb = quad * 4;               // D-layout row base for this lane

    const int ntiles = N_EDGES / 64;         // 12500 exact; grid 2500 -> 5 iters/block
    for (int t = blockIdx.x; t < ntiles; t += gridDim.x) {
        const int ebase = t * 64 + wave * 16;

        int sidx = 0, didx = 0;
        float sqd = 0.f;
        if (lane < 16) {
            int e = ebase + lane;
            sidx = src[e];
            didx = dst[e];
            float dx = getf(xpos, sidx * 3 + 0, isb) - getf(xpos, didx * 3 + 0, isb);
            float dy = getf(xpos, sidx * 3 + 1, isb) - getf(xpos, didx * 3 + 1, isb);
            float dz = getf(xpos, sidx * 3 + 2, isb) - getf(xpos, didx * 3 + 2, isb);
            sqd = dx * dx + dy * dy + dz * dz;
        }
        const int sn     = __shfl(sidx, l15);
        const int dn_row = __shfl(didx, l15);

        // ---- layer 1: [16x128] @ [128x64], A straight from global ----
        floatx4 acc[4];
        #pragma unroll
        for (int nt = 0; nt < 4; ++nt) acc[nt] = (floatx4){0.f, 0.f, 0.f, 0.f};
        #pragma unroll
        for (int c = 0; c < 4; ++c) {
            const int node = (c < 2) ? sn : dn_row;
            short8 a = get8bf(feat, node * 64 + (c & 1) * 32 + quad * 8, isb);
            #pragma unroll
            for (int nt = 0; nt < 4; ++nt)
                acc[nt] = __builtin_amdgcn_mfma_f32_16x16x32_bf16(a, bw1[c][nt], acc[nt], 0, 0, 0);
        }

        // ---- epilogue 1: + b1 + sqd*W1[128], relu, -> bf16 A2 tile in LDS ----
        float sq[4];
        #pragma unroll
        for (int r = 0; r < 4; ++r) sq[r] = __shfl(sqd, rowb + r);
        #pragma unroll
        for (int nt = 0; nt < 4; ++nt) {
            #pragma unroll
            for (int r = 0; r < 4; ++r) {
                float v = acc[nt][r] + b1r[nt] + sq[r] * w1lr[nt];
                v = fmaxf(v, 0.f);
                sA2[wave][rowb + r][nt * 16 + l15] = (short)f2bf(v);
            }
        }
        COMPILER_FENCE();
        WAIT_LDS();          // LDS writes committed; wave-local, no barrier needed

        // ---- layer 2: [16x64] @ [64x64] ----
        floatx4 acc2[4];
        #pragma unroll
        for (int nt = 0; nt < 4; ++nt) acc2[nt] = (floatx4){0.f, 0.f, 0.f, 0.f};
        #pragma unroll
        for (int c = 0; c < 2; ++c) {
            short8 a = *reinterpret_cast<const short8*>(&sA2[wave][l15][c * 32 + quad * 8]);
            #pragma unroll
            for (int nt = 0; nt < 4; ++nt)
                acc2[nt] = __builtin_amdgcn_mfma_f32_16x16x32_bf16(a, bw2[c][nt], acc2[nt], 0, 0, 0);
        }
        COMPILER_FENCE();    // keep next-iter LDS writes below these reads

        // ---- epilogue 2: relu, gate = sigmoid(m@we+be), gated scatter ----
        float mval[4][4];
        float part[4] = {0.f, 0.f, 0.f, 0.f};
        #pragma unroll
        for (int nt = 0; nt < 4; ++nt) {
            #pragma unroll
            for (int r = 0; r < 4; ++r) {
                float v = fmaxf(acc2[nt][r] + b2r[nt], 0.f);
                mval[nt][r] = v;
                part[r] += v * wer[nt];
            }
        }
        #pragma unroll
        for (int off = 1; off < 16; off <<= 1) {
            #pragma unroll
            for (int r = 0; r < 4; ++r) part[r] += __shfl_xor(part[r], off);
        }
        #pragma unroll
        for (int r = 0; r < 4; ++r) {
            int dn = __shfl(didx, rowb + r);
            float g = 1.f / (1.f + __expf(-(part[r] + ber)));
            unsigned int base = (unsigned int)dn * 64u;
            if (base + 64u <= msum_cap) {
                #pragma unroll
                for (int nt = 0; nt < 4; ++nt)
                    unsafeAtomicAdd(&msum[base + nt * 16 + l15], mval[nt][r] * g);
            }
        }
    }
}

// ---------------------------------------------------------------------------
// Node kernel, MFMA version: per wave a 16-node M-tile.
//   h = msum + feat (f32, ->bf16 frag); out = relu(h@U1+c1)@U2+c2 + feat
// Same wave-local LDS re-layout, no block barriers.
// ---------------------------------------------------------------------------
__global__ __launch_bounds__(256, 4) void node_kernel(
    const float* __restrict__ msum,
    const void* __restrict__ feat,
    const void* __restrict__ U1,
    const void* __restrict__ c1v,
    const void* __restrict__ U2,
    const void* __restrict__ c2v,
    void* __restrict__ out,
    unsigned int msum_cap)
{
    __shared__ __align__(16) short sT[4][16][72];

    const int isb  = detect_is_bf16((const unsigned short*)feat);
    const int tid  = threadIdx.x;
    const int wave = tid >> 6;
    const int lane = tid & 63;
    const int l15  = lane & 15;
    const int quad = lane >> 4;

    short8 u1f[2][4], u2f[2][4];
    #pragma unroll
    for (int c = 0; c < 2; ++c)
        #pragma unroll
        for (int nt = 0; nt < 4; ++nt) {
            short8 a, b;
            #pragma unroll
            for (int j = 0; j < 8; ++j) {
                int k = c * 32 + quad * 8 + j, n = nt * 16 + l15;
                a[j] = (short)f2bf(getf(U1, k * 64 + n, isb));
                b[j] = (short)f2bf(getf(U2, k * 64 + n, isb));
            }
            u1f[c][nt] = a; u2f[c][nt] = b;
        }
    float c1r[4], c2r[4];
    #pragma unroll
    for (int nt = 0; nt < 4; ++nt) {
        c1r[nt] = getf(c1v, nt * 16 + l15, isb);
        c2r[nt] = getf(c2v, nt * 16 + l15, isb);
    }
    const int rowb = quad * 4;

    const int ntile = (N_NODES + 15) / 16;   // 3125 exact
    const int t = blockIdx.x * 4 + wave;
    if (t < ntile) {
        const int node = t * 16 + l15;       // this lane's A-row

        // ---- build h fragments: 8 contiguous k at k0 = c*32 + quad*8 ----
        short8 ah[2];
        #pragma unroll
        for (int c = 0; c < 2; ++c) {
            unsigned int off = (unsigned int)node * 64u + c * 32 + quad * 8;
            float hv[8];
            if (isb) {
                short8 fv = *reinterpret_cast<const short8*>((const short*)feat + off);
                #pragma unroll
                for (int j = 0; j < 8; ++j)
                    hv[j] = bf2f((unsigned short)fv[j]);
            } else {
                float4 f0 = *reinterpret_cast<const float4*>((const float*)feat + off);
                float4 f1 = *reinterpret_cast<const float4*>((const float*)feat + off + 4);
                hv[0] = f0.x; hv[1] = f0.y; hv[2] = f0.z; hv[3] = f0.w;
                hv[4] = f1.x; hv[5] = f1.y; hv[6] = f1.z; hv[7] = f1.w;
            }
            float4 m0 = *reinterpret_cast<const float4*>(msum + off);
            float4 m1 = *reinterpret_cast<const float4*>(msum + off + 4);
            hv[0] += m0.x; hv[1] += m0.y; hv[2] += m0.z; hv[3] += m0.w;
            hv[4] += m1.x; hv[5] += m1.y; hv[6] += m1.z; hv[7] += m1.w;
            short8 a;
            #pragma unroll
            for (int j = 0; j < 8; ++j) a[j] = (short)f2bf(hv[j]);
            ah[c] = a;
        }

        // ---- layer 1: relu(h@U1+c1) ----
        floatx4 acc[4];
        #pragma unroll
        for (int nt = 0; nt < 4; ++nt) acc[nt] = (floatx4){0.f, 0.f, 0.f, 0.f};
        #pragma unroll
        for (int c = 0; c < 2; ++c)
            #pragma unroll
            for (int nt = 0; nt < 4; ++nt)
                acc[nt] = __builtin_amdgcn_mfma_f32_16x16x32_bf16(ah[c], u1f[c][nt], acc[nt], 0, 0, 0);

        #pragma unroll
        for (int nt = 0; nt < 4; ++nt)
            #pragma unroll
            for (int r = 0; r < 4; ++r) {
                float v = fmaxf(acc[nt][r] + c1r[nt], 0.f);
                sT[wave][rowb + r][nt * 16 + l15] = (short)f2bf(v);
            }
        COMPILER_FENCE();
        WAIT_LDS();

        // ---- layer 2: t@U2 + c2 + feat ----
        floatx4 acc2[4];
        #pragma unroll
        for (int nt = 0; nt < 4; ++nt) acc2[nt] = (floatx4){0.f, 0.f, 0.f, 0.f};
        #pragma unroll
        for (int c = 0; c < 2; ++c) {
            short8 a = *reinterpret_cast<const short8*>(&sT[wave][l15][c * 32 + quad * 8]);
            #pragma unroll
            for (int nt = 0; nt < 4; ++nt)
                acc2[nt] = __builtin_amdgcn_mfma_f32_16x16x32_bf16(a, u2f[c][nt], acc2[nt], 0, 0, 0);
        }
        COMPILER_FENCE();

        #pragma unroll
        for (int r = 0; r < 4; ++r) {
            unsigned int row = (unsigned int)(t * 16 + rowb + r);
            #pragma unroll
            for (int nt = 0; nt < 4; ++nt) {
                unsigned int off = row * 64u + nt * 16 + l15;
                float v = acc2[nt][r] + c2r[nt] + getf(feat, off, isb);
                if (isb) ((unsigned short*)out)[off] = f2bf(v);
                else     ((float*)out)[off] = v;
            }
        }
    }
}

extern "C" void kernel_launch(void* const* d_in, const int* in_sizes, int n_in,
                              void* d_out, int out_size, void* d_ws, size_t ws_size,
                              hipStream_t stream) {
    const void* feat = d_in[0];
    const void* x    = d_in[1];
    const int* src   = (const int*)d_in[2];
    const int* dst   = (const int*)d_in[3];
    const void* W1   = d_in[4];
    const void* b1   = d_in[5];
    const void* W2   = d_in[6];
    const void* b2   = d_in[7];
    const void* we   = d_in[8];
    const void* be   = d_in[9];
    const void* U1   = d_in[10];
    const void* c1   = d_in[11];
    const void* U2   = d_in[12];
    const void* c2   = d_in[13];
    float* msum      = (float*)d_ws;

    size_t need = (size_t)N_NODES * HDIM * sizeof(float);
    size_t clr  = need < ws_size ? need : ws_size;
    unsigned int cap = (unsigned int)(ws_size / sizeof(float));
    if (cap > (unsigned int)(N_NODES * HDIM)) cap = (unsigned int)(N_NODES * HDIM);

    hipMemsetAsync(msum, 0, clr, stream);
    edge_kernel<<<2500, 256, 0, stream>>>(feat, x, src, dst, W1, b1, W2, b2, we, be, msum, cap);
    node_kernel<<<((N_NODES + 15) / 16 + 3) / 4, 256, 0, stream>>>(msum, feat, U1, c1, U2, c2, d_out, cap);
}

// Round 5
// 315.410 us; speedup vs baseline: 1.5488x; 1.5488x over previous
//
#include <hip/hip_runtime.h>
#include <hip/hip_bf16.h>
#include <stdint.h>

#define N_NODES 50000
#define N_EDGES 800000
#define HDIM 64

typedef __attribute__((ext_vector_type(8))) short short8;
typedef __attribute__((ext_vector_type(4))) float floatx4;

__device__ __forceinline__ float bf2f(unsigned short u) {
    union { unsigned int i; float f; } v; v.i = ((unsigned int)u) << 16; return v.f;
}
__device__ __forceinline__ unsigned short f2bf(float f) {
    __hip_bfloat16 h = __float2bfloat16(f);
    return *reinterpret_cast<unsigned short*>(&h);
}

// Detect whether a float tensor was stored as bf16 (1) or f32 (0).
__device__ __forceinline__ int detect_is_bf16(const unsigned short* p) {
    int cnt = 0;
    #pragma unroll
    for (int i = 0; i < 64; ++i) {
        unsigned short b = p[i];
        int e = (b >> 7) & 0xFF;
        cnt += ((e >= 97 && e <= 157) || (b & 0x7FFF) == 0) ? 1 : 0;
    }
    return cnt >= 56;
}

__device__ __forceinline__ float getf(const void* p, unsigned int i, int isb) {
    return isb ? bf2f(((const unsigned short*)p)[i]) : ((const float*)p)[i];
}

// 8 contiguous elements -> bf16 fragment
__device__ __forceinline__ short8 get8bf(const void* p, unsigned int i, int isb) {
    if (isb) {
        return *reinterpret_cast<const short8*>((const short*)p + i);
    } else {
        const float4 f0 = *reinterpret_cast<const float4*>((const float*)p + i);
        const float4 f1 = *reinterpret_cast<const float4*>((const float*)p + i + 4);
        short8 a;
        a[0] = (short)f2bf(f0.x); a[1] = (short)f2bf(f0.y);
        a[2] = (short)f2bf(f0.z); a[3] = (short)f2bf(f0.w);
        a[4] = (short)f2bf(f1.x); a[5] = (short)f2bf(f1.y);
        a[6] = (short)f2bf(f1.z); a[7] = (short)f2bf(f1.w);
        return a;
    }
}

// Compiler-only memory fence (free) — blocks LDS write/read reordering.
#define COMPILER_FENCE() asm volatile("" ::: "memory")
// HW wait: lgkmcnt(0) only — drains LDS writes without draining global ops.
#define WAIT_LDS() __builtin_amdgcn_s_waitcnt(0xC07F)

// ---------------------------------------------------------------------------
// Edge kernel: per wave, a 16-edge MFMA M-tile. No block barriers in the loop
// (wave-local LDS re-layout, fence + lgkmcnt only). Atomics fire-and-forget.
// __launch_bounds__(256,2): 120 VGPR alloc, NO spill (m r4: (256,4) capped
// VGPR at 64 and spilled the weight fragments -> +744 MB scratch traffic).
// ---------------------------------------------------------------------------
__global__ __launch_bounds__(256, 2) void edge_kernel(
    const void* __restrict__ feat,    // [N][64] bf16 or f32
    const void* __restrict__ xpos,    // [N][3]
    const int* __restrict__ src,
    const int* __restrict__ dst,
    const void* __restrict__ W1,      // [129][64] row-major
    const void* __restrict__ b1,
    const void* __restrict__ W2,      // [64][64]
    const void* __restrict__ b2,
    const void* __restrict__ we,
    const void* __restrict__ be,
    float* __restrict__ msum,         // [N][64] f32 (zeroed)
    unsigned int msum_cap)
{
    __shared__ __align__(16) short sA2[4][16][72];  // per-wave 16x64 tile

    const int isb  = detect_is_bf16((const unsigned short*)feat);
    const int tid  = threadIdx.x;
    const int wave = tid >> 6;
    const int lane = tid & 63;
    const int l15  = lane & 15;
    const int quad = lane >> 4;

    // ---- persistent B fragments: lane holds B[k=quad*8+j][n=l15+16*nt] ----
    short8 bw1[4][4];
    #pragma unroll
    for (int c = 0; c < 4; ++c)
        #pragma unroll
        for (int nt = 0; nt < 4; ++nt) {
            short8 b;
            #pragma unroll
            for (int j = 0; j < 8; ++j)
                b[j] = (short)f2bf(getf(W1, (c * 32 + quad * 8 + j) * 64 + nt * 16 + l15, isb));
            bw1[c][nt] = b;
        }
    short8 bw2[2][4];
    #pragma unroll
    for (int c = 0; c < 2; ++c)
        #pragma unroll
        for (int nt = 0; nt < 4; ++nt) {
            short8 b;
            #pragma unroll
            for (int j = 0; j < 8; ++j)
                b[j] = (short)f2bf(getf(W2, (c * 32 + quad * 8 + j) * 64 + nt * 16 + l15, isb));
            bw2[c][nt] = b;
        }
    float b1r[4], w1lr[4], b2r[4], wer[4];
    #pragma unroll
    for (int nt = 0; nt < 4; ++nt) {
        int n = nt * 16 + l15;
        b1r[nt]  = getf(b1, n, isb);
        w1lr[nt] = getf(W1, 128 * 64 + n, isb);   // sqd row of W1
        b2r[nt]  = getf(b2, n, isb);
        wer[nt]  = getf(we, n, isb);
    }
    const float ber = getf(be, 0, isb);
    const int rowb = quad * 4;               // D-layout row base for this lane

    const int ntiles = N_EDGES / 64;         // 12500 exact; grid 2500 -> 5 iters/block
    for (int t = blockIdx.x; t < ntiles; t += gridDim.x) {
        const int ebase = t * 64 + wave * 16;

        int sidx = 0, didx = 0;
        float sqd = 0.f;
        if (lane < 16) {
            int e = ebase + lane;
            sidx = src[e];
            didx = dst[e];
            float dx = getf(xpos, sidx * 3 + 0, isb) - getf(xpos, didx * 3 + 0, isb);
            float dy = getf(xpos, sidx * 3 + 1, isb) - getf(xpos, didx * 3 + 1, isb);
            float dz = getf(xpos, sidx * 3 + 2, isb) - getf(xpos, didx * 3 + 2, isb);
            sqd = dx * dx + dy * dy + dz * dz;
        }
        const int sn     = __shfl(sidx, l15);
        const int dn_row = __shfl(didx, l15);

        // ---- layer 1: [16x128] @ [128x64], A straight from global ----
        floatx4 acc[4];
        #pragma unroll
        for (int nt = 0; nt < 4; ++nt) acc[nt] = (floatx4){0.f, 0.f, 0.f, 0.f};
        #pragma unroll
        for (int c = 0; c < 4; ++c) {
            const int node = (c < 2) ? sn : dn_row;
            short8 a = get8bf(feat, node * 64 + (c & 1) * 32 + quad * 8, isb);
            #pragma unroll
            for (int nt = 0; nt < 4; ++nt)
                acc[nt] = __builtin_amdgcn_mfma_f32_16x16x32_bf16(a, bw1[c][nt], acc[nt], 0, 0, 0);
        }

        // ---- epilogue 1: + b1 + sqd*W1[128], relu, -> bf16 A2 tile in LDS ----
        float sq[4];
        #pragma unroll
        for (int r = 0; r < 4; ++r) sq[r] = __shfl(sqd, rowb + r);
        #pragma unroll
        for (int nt = 0; nt < 4; ++nt) {
            #pragma unroll
            for (int r = 0; r < 4; ++r) {
                float v = acc[nt][r] + b1r[nt] + sq[r] * w1lr[nt];
                v = fmaxf(v, 0.f);
                sA2[wave][rowb + r][nt * 16 + l15] = (short)f2bf(v);
            }
        }
        COMPILER_FENCE();
        WAIT_LDS();          // wave-local ordering; no block barrier

        // ---- layer 2: [16x64] @ [64x64] ----
        floatx4 acc2[4];
        #pragma unroll
        for (int nt = 0; nt < 4; ++nt) acc2[nt] = (floatx4){0.f, 0.f, 0.f, 0.f};
        #pragma unroll
        for (int c = 0; c < 2; ++c) {
            short8 a = *reinterpret_cast<const short8*>(&sA2[wave][l15][c * 32 + quad * 8]);
            #pragma unroll
            for (int nt = 0; nt < 4; ++nt)
                acc2[nt] = __builtin_amdgcn_mfma_f32_16x16x32_bf16(a, bw2[c][nt], acc2[nt], 0, 0, 0);
        }
        COMPILER_FENCE();    // keep next-iter LDS writes below these reads

        // ---- epilogue 2: relu, gate = sigmoid(m@we+be), gated scatter ----
        float mval[4][4];
        float part[4] = {0.f, 0.f, 0.f, 0.f};
        #pragma unroll
        for (int nt = 0; nt < 4; ++nt) {
            #pragma unroll
            for (int r = 0; r < 4; ++r) {
                float v = fmaxf(acc2[nt][r] + b2r[nt], 0.f);
                mval[nt][r] = v;
                part[r] += v * wer[nt];
            }
        }
        #pragma unroll
        for (int off = 1; off < 16; off <<= 1) {
            #pragma unroll
            for (int r = 0; r < 4; ++r) part[r] += __shfl_xor(part[r], off);
        }
        #pragma unroll
        for (int r = 0; r < 4; ++r) {
            int dn = __shfl(didx, rowb + r);
            float g = 1.f / (1.f + __expf(-(part[r] + ber)));
            unsigned int base = (unsigned int)dn * 64u;
            if (base + 64u <= msum_cap) {
                #pragma unroll
                for (int nt = 0; nt < 4; ++nt)
                    unsafeAtomicAdd(&msum[base + nt * 16 + l15], mval[nt][r] * g);
            }
        }
    }
}

// ---------------------------------------------------------------------------
// Node kernel, MFMA version: per wave a 16-node M-tile, no block barriers.
// ---------------------------------------------------------------------------
__global__ __launch_bounds__(256, 2) void node_kernel(
    const float* __restrict__ msum,
    const void* __restrict__ feat,
    const void* __restrict__ U1,
    const void* __restrict__ c1v,
    const void* __restrict__ U2,
    const void* __restrict__ c2v,
    void* __restrict__ out,
    unsigned int msum_cap)
{
    __shared__ __align__(16) short sT[4][16][72];

    const int isb  = detect_is_bf16((const unsigned short*)feat);
    const int tid  = threadIdx.x;
    const int wave = tid >> 6;
    const int lane = tid & 63;
    const int l15  = lane & 15;
    const int quad = lane >> 4;

    short8 u1f[2][4], u2f[2][4];
    #pragma unroll
    for (int c = 0; c < 2; ++c)
        #pragma unroll
        for (int nt = 0; nt < 4; ++nt) {
            short8 a, b;
            #pragma unroll
            for (int j = 0; j < 8; ++j) {
                int k = c * 32 + quad * 8 + j, n = nt * 16 + l15;
                a[j] = (short)f2bf(getf(U1, k * 64 + n, isb));
                b[j] = (short)f2bf(getf(U2, k * 64 + n, isb));
            }
            u1f[c][nt] = a; u2f[c][nt] = b;
        }
    float c1r[4], c2r[4];
    #pragma unroll
    for (int nt = 0; nt < 4; ++nt) {
        c1r[nt] = getf(c1v, nt * 16 + l15, isb);
        c2r[nt] = getf(c2v, nt * 16 + l15, isb);
    }
    const int rowb = quad * 4;

    const int ntile = (N_NODES + 15) / 16;   // 3125 exact
    const int t = blockIdx.x * 4 + wave;
    if (t < ntile) {
        const int node = t * 16 + l15;       // this lane's A-row

        // ---- build h fragments: 8 contiguous k at k0 = c*32 + quad*8 ----
        short8 ah[2];
        #pragma unroll
        for (int c = 0; c < 2; ++c) {
            unsigned int off = (unsigned int)node * 64u + c * 32 + quad * 8;
            float hv[8];
            if (isb) {
                short8 fv = *reinterpret_cast<const short8*>((const short*)feat + off);
                #pragma unroll
                for (int j = 0; j < 8; ++j)
                    hv[j] = bf2f((unsigned short)fv[j]);
            } else {
                float4 f0 = *reinterpret_cast<const float4*>((const float*)feat + off);
                float4 f1 = *reinterpret_cast<const float4*>((const float*)feat + off + 4);
                hv[0] = f0.x; hv[1] = f0.y; hv[2] = f0.z; hv[3] = f0.w;
                hv[4] = f1.x; hv[5] = f1.y; hv[6] = f1.z; hv[7] = f1.w;
            }
            float4 m0 = *reinterpret_cast<const float4*>(msum + off);
            float4 m1 = *reinterpret_cast<const float4*>(msum + off + 4);
            hv[0] += m0.x; hv[1] += m0.y; hv[2] += m0.z; hv[3] += m0.w;
            hv[4] += m1.x; hv[5] += m1.y; hv[6] += m1.z; hv[7] += m1.w;
            short8 a;
            #pragma unroll
            for (int j = 0; j < 8; ++j) a[j] = (short)f2bf(hv[j]);
            ah[c] = a;
        }

        // ---- layer 1: relu(h@U1+c1) ----
        floatx4 acc[4];
        #pragma unroll
        for (int nt = 0; nt < 4; ++nt) acc[nt] = (floatx4){0.f, 0.f, 0.f, 0.f};
        #pragma unroll
        for (int c = 0; c < 2; ++c)
            #pragma unroll
            for (int nt = 0; nt < 4; ++nt)
                acc[nt] = __builtin_amdgcn_mfma_f32_16x16x32_bf16(ah[c], u1f[c][nt], acc[nt], 0, 0, 0);

        #pragma unroll
        for (int nt = 0; nt < 4; ++nt)
            #pragma unroll
            for (int r = 0; r < 4; ++r) {
                float v = fmaxf(acc[nt][r] + c1r[nt], 0.f);
                sT[wave][rowb + r][nt * 16 + l15] = (short)f2bf(v);
            }
        COMPILER_FENCE();
        WAIT_LDS();

        // ---- layer 2: t@U2 + c2 + feat ----
        floatx4 acc2[4];
        #pragma unroll
        for (int nt = 0; nt < 4; ++nt) acc2[nt] = (floatx4){0.f, 0.f, 0.f, 0.f};
        #pragma unroll
        for (int c = 0; c < 2; ++c) {
            short8 a = *reinterpret_cast<const short8*>(&sT[wave][l15][c * 32 + quad * 8]);
            #pragma unroll
            for (int nt = 0; nt < 4; ++nt)
                acc2[nt] = __builtin_amdgcn_mfma_f32_16x16x32_bf16(a, u2f[c][nt], acc2[nt], 0, 0, 0);
        }
        COMPILER_FENCE();

        #pragma unroll
        for (int r = 0; r < 4; ++r) {
            unsigned int row = (unsigned int)(t * 16 + rowb + r);
            #pragma unroll
            for (int nt = 0; nt < 4; ++nt) {
                unsigned int off = row * 64u + nt * 16 + l15;
                float v = acc2[nt][r] + c2r[nt] + getf(feat, off, isb);
                if (isb) ((unsigned short*)out)[off] = f2bf(v);
                else     ((float*)out)[off] = v;
            }
        }
    }
}

extern "C" void kernel_launch(void* const* d_in, const int* in_sizes, int n_in,
                              void* d_out, int out_size, void* d_ws, size_t ws_size,
                              hipStream_t stream) {
    const void* feat = d_in[0];
    const void* x    = d_in[1];
    const int* src   = (const int*)d_in[2];
    const int* dst   = (const int*)d_in[3];
    const void* W1   = d_in[4];
    const void* b1   = d_in[5];
    const void* W2   = d_in[6];
    const void* b2   = d_in[7];
    const void* we   = d_in[8];
    const void* be   = d_in[9];
    const void* U1   = d_in[10];
    const void* c1   = d_in[11];
    const void* U2   = d_in[12];
    const void* c2   = d_in[13];
    float* msum      = (float*)d_ws;

    size_t need = (size_t)N_NODES * HDIM * sizeof(float);
    size_t clr  = need < ws_size ? need : ws_size;
    unsigned int cap = (unsigned int)(ws_size / sizeof(float));
    if (cap > (unsigned int)(N_NODES * HDIM)) cap = (unsigned int)(N_NODES * HDIM);

    hipMemsetAsync(msum, 0, clr, stream);
    edge_kernel<<<2500, 256, 0, stream>>>(feat, x, src, dst, W1, b1, W2, b2, we, be, msum, cap);
    node_kernel<<<((N_NODES + 15) / 16 + 3) / 4, 256, 0, stream>>>(msum, feat, U1, c1, U2, c2, d_out, cap);
}